// Round 9
// baseline (171.768 us; speedup 1.0000x reference)
//
#include <hip/hip_runtime.h>
#include <cmath>

namespace {
constexpr int H = 256, W = 256, HWp = H * W;
constexpr size_t PLANE = (size_t)4 * HWp * 64 * 2;  // one NHWC fp16 tensor, bytes
constexpr size_t NEED_FAST = 73728 + 2 * PLANE + (1u << 20);
}

typedef _Float16 f16;
typedef unsigned int u32;
typedef __attribute__((ext_vector_type(4))) _Float16 f16x4;
typedef __attribute__((ext_vector_type(8))) _Float16 f16x8;
typedef __attribute__((ext_vector_type(4))) float f32x4;
typedef __attribute__((ext_vector_type(4))) unsigned int u32x4;

__device__ __forceinline__ void dma16(const char* g, char* l) {
    __builtin_amdgcn_global_load_lds(
        (const __attribute__((address_space(1))) u32*)g,
        (__attribute__((address_space(3))) u32*)l, 16, 0, 0);
}

// K_wt: w1 [co][ci][3][3] fp32 -> w1tb [k9][co][ci] fp16
__global__ void k_wt(const float* __restrict__ w1, f16* __restrict__ w1tb) {
    int i = blockIdx.x * 256 + threadIdx.x;
    if (i >= 64 * 576) return;
    int co = i / 576, r = i - co * 576;
    int ci = r / 9, k9 = r - ci * 9;
    w1tb[(k9 * 64 + co) * 64 + ci] = (f16)w1[i];
}

// K_xt: both tensors in one launch. blockIdx.y: 0..3 -> z_real->Xt_r, 4..7 -> z_imag->Xt_i.
__global__ __launch_bounds__(256) void k_xt2(const float* __restrict__ zr,
                                             const float* __restrict__ zi,
                                             f16* __restrict__ Xt_r,
                                             f16* __restrict__ Xt_i) {
    __shared__ f16 tile[64][80];
    const int t = threadIdx.x;
    const int p0 = blockIdx.x * 64;
    const int bb = blockIdx.y & 3;
    const bool im = blockIdx.y >= 4;
    const float* x = im ? zi : zr;
    f16* dst = im ? Xt_i : Xt_r;
    const size_t base = (size_t)bb * 64 * HWp;
#pragma unroll
    for (int r = 0; r < 4; ++r) {
        int q = r * 256 + t;
        int ci = q >> 4, px4 = (q & 15) * 4;
        f32x4 v = *reinterpret_cast<const f32x4*>(x + base + (size_t)ci * HWp + p0 + px4);
#pragma unroll
        for (int j = 0; j < 4; ++j) tile[px4 + j][ci] = (f16)v[j];
    }
    __syncthreads();
    const int px = t >> 2, q = t & 3;
    u32x4* d = reinterpret_cast<u32x4*>(dst + ((size_t)bb * HWp + p0 + px) * 64 + q * 16);
    const u32x4* s = reinterpret_cast<const u32x4*>(&tile[px][q * 16]);
    d[0] = s[0];
    d[1] = s[1];
}

// K1 v4: conv1 via MFMA. A-row only in LDS (18KB, global_load_lds, XOR-swizzled
// reads); W fragments straight from global (L1/L2-resident 72KB, coalesced
// 2KB/wave). Block = 1 row x 128 px x 64 co; 4 waves (2px x 2co).
__global__ __launch_bounds__(256, 3) void k_conv1(
        const f16* __restrict__ Xt,    // [B][HWp][64] fp16
        const f16* __restrict__ w1tb,  // [9][64co][64ci] fp16
        const float* __restrict__ b1,
        f16* __restrict__ act) {       // [B][HWp][64] fp16
    __shared__ __align__(16) char lds[18432];

    const int tid = threadIdx.x;
    const int lane = tid & 63, wid = tid >> 6;
    const int lr = lane & 15, lg = lane >> 4;
    const int wpx = wid & 1, wco = wid >> 1;

    const int bid = blockIdx.x;                  // 0..2047
    const int swz = (bid & 7) * 256 + (bid >> 3);
    const int b = swz >> 9;
    const int y = (swz >> 1) & 255;
    const int x0 = (swz & 1) << 7;

    const int swzb = (lane ^ ((lane >> 3) & 7)) << 4;

    f32x4 acc[4][2];
#pragma unroll
    for (int m = 0; m < 4; ++m)
#pragma unroll
        for (int n = 0; n < 2; ++n) acc[m][n] = (f32x4)0.f;

    const f16x8 zf = (f16x8)(f16)0.f;
    // W base for this wave: co = wco*32 + n*16 + lr, ci = c*32 + lg*8
    const f16* Wbase = w1tb + (size_t)(wco * 32 + lr) * 64 + lg * 8;

    for (int dyi = 0; dyi < 3; ++dyi) {
        const int yy = y + dyi - 1;
        if ((unsigned)yy >= 256u) continue;      // block-uniform zero-pad skip

        __syncthreads();                          // LDS reuse guard
        {
            const char* asrc = (const char*)Xt +
                ((((size_t)b * 256 + yy) * 256 + x0 - 8) * 128) + swzb;
            for (int j = wid; j < 18; j += 4)
                dma16(asrc + j * 1024, lds + j * 1024);
        }
        __syncthreads();                          // drain DMA

#pragma unroll
        for (int kx = 0; kx < 3; ++kx) {
            const int dx = kx - 1;
            const int gx0 = x0 + wpx * 64 + lr + dx;
            const bool ok0 = (unsigned)gx0 < 256u;
            const bool ok3 = (unsigned)(gx0 + 48) < 256u;
            const int arow = (8 + wpx * 64 + lr + dx) << 7;
            const int axor = (lr + dx) & 7;
            const f16* Wk = Wbase + (size_t)(dyi * 3 + kx) * 4096;
#pragma unroll
            for (int c = 0; c < 2; ++c) {
                const int abase = arow + (((c * 4 + lg) ^ axor) << 4);
                f16x8 A0 = *reinterpret_cast<const f16x8*>(lds + abase);
                f16x8 A1 = *reinterpret_cast<const f16x8*>(lds + abase + 2048);
                f16x8 A2 = *reinterpret_cast<const f16x8*>(lds + abase + 4096);
                f16x8 A3 = *reinterpret_cast<const f16x8*>(lds + abase + 6144);
                const f16* Wc = Wk + c * 32;
                f16x8 W0 = *reinterpret_cast<const f16x8*>(Wc);
                f16x8 W1 = *reinterpret_cast<const f16x8*>(Wc + 1024);  // +16 co rows
                A0 = ok0 ? A0 : zf;
                A3 = ok3 ? A3 : zf;
                acc[0][0] = __builtin_amdgcn_mfma_f32_16x16x32_f16(W0, A0, acc[0][0], 0, 0, 0);
                acc[0][1] = __builtin_amdgcn_mfma_f32_16x16x32_f16(W1, A0, acc[0][1], 0, 0, 0);
                acc[1][0] = __builtin_amdgcn_mfma_f32_16x16x32_f16(W0, A1, acc[1][0], 0, 0, 0);
                acc[1][1] = __builtin_amdgcn_mfma_f32_16x16x32_f16(W1, A1, acc[1][1], 0, 0, 0);
                acc[2][0] = __builtin_amdgcn_mfma_f32_16x16x32_f16(W0, A2, acc[2][0], 0, 0, 0);
                acc[2][1] = __builtin_amdgcn_mfma_f32_16x16x32_f16(W1, A2, acc[2][1], 0, 0, 0);
                acc[3][0] = __builtin_amdgcn_mfma_f32_16x16x32_f16(W0, A3, acc[3][0], 0, 0, 0);
                acc[3][1] = __builtin_amdgcn_mfma_f32_16x16x32_f16(W1, A3, acc[3][1], 0, 0, 0);
            }
        }
    }

    float bias[2][4];
#pragma unroll
    for (int n = 0; n < 2; ++n) {
        f32x4 bv = *reinterpret_cast<const f32x4*>(b1 + wco * 32 + n * 16 + lg * 4);
#pragma unroll
        for (int r = 0; r < 4; ++r) bias[n][r] = bv[r];
    }
    const size_t row_base = ((size_t)b * 256 + y) * 256;
#pragma unroll
    for (int m = 0; m < 4; ++m) {
        f16* ap = act + (row_base + x0 + wpx * 64 + m * 16 + lr) * 64 + wco * 32 + lg * 4;
#pragma unroll
        for (int n = 0; n < 2; ++n) {
            f16x4 o;
#pragma unroll
            for (int r = 0; r < 4; ++r) {
                float v = acc[m][n][r] + bias[n][r];
                v = v / (1.f + __expf(-v));
                o[r] = (f16)v;
            }
            *reinterpret_cast<f16x4*>(ap + n * 16) = o;
        }
    }
}

// K2: conv2 (64->1) + *dt -> psi. NHWC fp16 input, f16x8 vector loads.
__global__ __launch_bounds__(256) void k_conv2(
        const f16* __restrict__ act, const float* __restrict__ w2,
        const float* __restrict__ b2, const float* __restrict__ dtp,
        float* __restrict__ psi) {
    const int tx = threadIdx.x & 31, ty = threadIdx.x >> 5;
    const int px = blockIdx.x * 32 + tx;
    const int py = blockIdx.y * 8 + ty;
    const int b = blockIdx.z;

    float a0 = 0.f, a1 = 0.f, a2 = 0.f, a3 = 0.f;
#pragma unroll
    for (int dy = -1; dy <= 1; ++dy) {
        const int yy = py + dy;
        if ((unsigned)yy >= (unsigned)H) continue;
#pragma unroll
        for (int dx = -1; dx <= 1; ++dx) {
            const int xx = px + dx;
            const int k9 = (dy + 1) * 3 + (dx + 1);
            if ((unsigned)xx < (unsigned)W) {
                const f16x8* ap = reinterpret_cast<const f16x8*>(
                    act + (((size_t)b * H + yy) * W + xx) * 64);
                const float* wp = w2 + k9;
#pragma unroll
                for (int g = 0; g < 8; ++g) {
                    const f16x8 v = ap[g];
                    const int cb = g * 8;
                    a0 = fmaf((float)v[0], wp[(cb + 0) * 9], a0);
                    a1 = fmaf((float)v[1], wp[(cb + 1) * 9], a1);
                    a2 = fmaf((float)v[2], wp[(cb + 2) * 9], a2);
                    a3 = fmaf((float)v[3], wp[(cb + 3) * 9], a3);
                    a0 = fmaf((float)v[4], wp[(cb + 4) * 9], a0);
                    a1 = fmaf((float)v[5], wp[(cb + 5) * 9], a1);
                    a2 = fmaf((float)v[6], wp[(cb + 6) * 9], a2);
                    a3 = fmaf((float)v[7], wp[(cb + 7) * 9], a3);
                }
            }
        }
    }
    psi[((size_t)b * H + py) * W + px] = ((a0 + a1) + (a2 + a3) + b2[0]) * dtp[0];
}

// K3 v3: block = 1 row-half (128 px) x ALL 128 channels (proven R8).
__global__ __launch_bounds__(256, 4) void k_sample3(
        const f16* __restrict__ Xt_r, const f16* __restrict__ Xt_i,
        const float* __restrict__ psi, float* __restrict__ out) {
    __shared__ int   s_off[4][128];
    __shared__ float s_w[4][128];
    __shared__ __align__(16) float s_stage[64][132];

    const int tid = threadIdx.x;
    const int bid = blockIdx.x;                  // 0..2047
    const int swz = (bid & 7) * 256 + (bid >> 3);
    const int seg = swz & 1, y = (swz >> 1) & 255, b = swz >> 9;
    const int x0 = seg * 128;

    if (tid < 128) {
        const int px = x0 + tid;
        const float* pb = psi + b * HWp;
        const int yp = min(y + 1, H - 1), ym = max(y - 1, 0);
        const int xp = min(px + 1, W - 1), xm = max(px - 1, 0);
        const float u = 0.5f * (pb[yp * W + px] - pb[ym * W + px]);
        const float v = -0.5f * (pb[y * W + xp] - pb[y * W + xm]);
        const float gx = (-1.f + 2.f * px / (float)(W - 1)) - u * (2.f / (float)W);
        const float gy = (-1.f + 2.f * y / (float)(H - 1)) - v * (2.f / (float)H);
        float ix = fminf(fmaxf((gx + 1.f) * 0.5f * (float)(W - 1), 0.f), (float)(W - 1));
        float iy = fminf(fmaxf((gy + 1.f) * 0.5f * (float)(H - 1), 0.f), (float)(H - 1));
        const float xf = floorf(ix), yf = floorf(iy);
        const float wx = ix - xf, wy = iy - yf;
        const int ix0 = (int)xf, iy0 = (int)yf;
        const int ix1 = min(ix0 + 1, W - 1), iy1 = min(iy0 + 1, H - 1);
        s_off[0][tid] = (iy0 * W + ix0) * 128;
        s_off[1][tid] = (iy0 * W + ix1) * 128;
        s_off[2][tid] = (iy1 * W + ix0) * 128;
        s_off[3][tid] = (iy1 * W + ix1) * 128;
        s_w[0][tid] = (1.f - wx) * (1.f - wy);
        s_w[1][tid] = wx * (1.f - wy);
        s_w[2][tid] = (1.f - wx) * wy;
        s_w[3][tid] = wx * wy;
    }
    __syncthreads();

    const int p = tid >> 1, s = tid & 1;
    const int o0 = s_off[0][p], o1 = s_off[1][p], o2 = s_off[2][p], o3 = s_off[3][p];
    const float w0 = s_w[0][p], w1 = s_w[1][p], w2 = s_w[2][p], w3 = s_w[3][p];
    const int cl = tid >> 5;
    const int pxq = (tid & 31) * 4;
    const size_t obase = (size_t)b * 128 * HWp + (size_t)y * W + x0 + pxq;

#pragma unroll
    for (int pl = 0; pl < 2; ++pl) {
        const char* base = (const char*)(pl ? Xt_i : Xt_r)
                         + (size_t)b * HWp * 128 + s * 64;
        const char* c0 = base + o0;
        const char* c1 = base + o1;
        const char* c2 = base + o2;
        const char* c3 = base + o3;
        f16x8 h00 = *(const f16x8*)(c0);      f16x8 h01 = *(const f16x8*)(c0 + 16);
        f16x8 h02 = *(const f16x8*)(c0 + 32); f16x8 h03 = *(const f16x8*)(c0 + 48);
        f16x8 h10 = *(const f16x8*)(c1);      f16x8 h11 = *(const f16x8*)(c1 + 16);
        f16x8 h12 = *(const f16x8*)(c1 + 32); f16x8 h13 = *(const f16x8*)(c1 + 48);
        f16x8 h20 = *(const f16x8*)(c2);      f16x8 h21 = *(const f16x8*)(c2 + 16);
        f16x8 h22 = *(const f16x8*)(c2 + 32); f16x8 h23 = *(const f16x8*)(c2 + 48);
        f16x8 h30 = *(const f16x8*)(c3);      f16x8 h31 = *(const f16x8*)(c3 + 16);
        f16x8 h32 = *(const f16x8*)(c3 + 32); f16x8 h33 = *(const f16x8*)(c3 + 48);

        const int rb = s << 5;
#pragma unroll
        for (int k = 0; k < 8; ++k) {
            s_stage[rb + k][p] = w0 * (float)h00[k] + w1 * (float)h10[k]
                               + w2 * (float)h20[k] + w3 * (float)h30[k];
            s_stage[rb + 8 + k][p] = w0 * (float)h01[k] + w1 * (float)h11[k]
                                   + w2 * (float)h21[k] + w3 * (float)h31[k];
            s_stage[rb + 16 + k][p] = w0 * (float)h02[k] + w1 * (float)h12[k]
                                    + w2 * (float)h22[k] + w3 * (float)h32[k];
            s_stage[rb + 24 + k][p] = w0 * (float)h03[k] + w1 * (float)h13[k]
                                    + w2 * (float)h23[k] + w3 * (float)h33[k];
        }
        __syncthreads();
#pragma unroll
        for (int k = 0; k < 8; ++k) {
            const int c = cl + (k << 3);
            f32x4 vv = *(const f32x4*)&s_stage[c][pxq];
            *(f32x4*)(out + obase + (size_t)(pl * 64 + c) * HWp) = vv;
        }
        __syncthreads();
    }
}

// K3 fallback: scalar gather from fp32 NCHW.
__global__ __launch_bounds__(256) void k_sample_fb(
        const float* __restrict__ zr, const float* __restrict__ zi,
        const float* __restrict__ psi, float* __restrict__ out) {
    const int tx = threadIdx.x & 31, ty = threadIdx.x >> 5;
    const int px = blockIdx.x * 32 + tx;
    const int py = blockIdx.y * 8 + ty;
    const int b  = blockIdx.z >> 3;
    const int c0 = (blockIdx.z & 7) * 16;

    const float* pb = psi + b * HWp;
    const int yp = min(py + 1, H - 1), ym = max(py - 1, 0);
    const int xp = min(px + 1, W - 1), xm = max(px - 1, 0);
    const float u = 0.5f * (pb[yp * W + px] - pb[ym * W + px]);
    const float v = -0.5f * (pb[py * W + xp] - pb[py * W + xm]);

    const float gx = (-1.f + 2.f * px / (float)(W - 1)) - u * (2.f / (float)W);
    const float gy = (-1.f + 2.f * py / (float)(H - 1)) - v * (2.f / (float)H);

    float ix = fminf(fmaxf((gx + 1.f) * 0.5f * (float)(W - 1), 0.f), (float)(W - 1));
    float iy = fminf(fmaxf((gy + 1.f) * 0.5f * (float)(H - 1), 0.f), (float)(H - 1));
    const float xf = floorf(ix), yf = floorf(iy);
    const float wx = ix - xf, wy = iy - yf;
    const int ix0 = (int)xf, iy0 = (int)yf;
    const int ix1 = min(ix0 + 1, W - 1), iy1 = min(iy0 + 1, H - 1);

    const int o00 = iy0 * W + ix0, o01 = iy0 * W + ix1;
    const int o10 = iy1 * W + ix0, o11 = iy1 * W + ix1;
    const float w00 = (1.f - wx) * (1.f - wy), w01 = wx * (1.f - wy);
    const float w10 = (1.f - wx) * wy, w11 = wx * wy;

    const float* src0 = (c0 < 64) ? (zr + (size_t)b * 64 * HWp + (size_t)c0 * HWp)
                                  : (zi + (size_t)b * 64 * HWp + (size_t)(c0 - 64) * HWp);
    float* ob = out + ((size_t)b * 128 + c0) * HWp + py * W + px;
#pragma unroll
    for (int c = 0; c < 16; ++c) {
        const float* p = src0 + (size_t)c * HWp;
        ob[(size_t)c * HWp] = p[o00] * w00 + p[o01] * w01 + p[o10] * w10 + p[o11] * w11;
    }
}

extern "C" void kernel_launch(void* const* d_in, const int* in_sizes, int n_in,
                              void* d_out, int out_size, void* d_ws, size_t ws_size,
                              hipStream_t stream) {
    const float* z_real = (const float*)d_in[0];
    const float* z_imag = (const float*)d_in[1];
    const float* dt     = (const float*)d_in[2];
    const float* w1     = (const float*)d_in[3];
    const float* b1     = (const float*)d_in[4];
    const float* w2     = (const float*)d_in[5];
    const float* b2     = (const float*)d_in[6];

    float* out = (float*)d_out;
    char* ws = (char*)d_ws;
    f16* w1tb = (f16*)ws;                       // 73728 B

    hipLaunchKernelGGL(k_wt, dim3(144), dim3(256), 0, stream, w1, w1tb);

    if (ws_size >= NEED_FAST) {
        // ws layout: w1tb | Xt_r | Xt_i | psi
        f16* Xt_r  = (f16*)(ws + 73728);
        f16* Xt_i  = (f16*)(ws + 73728 + PLANE);
        float* psi = (float*)(ws + 73728 + 2 * PLANE);
        f16* act   = (f16*)d_out;   // consumed by conv2 before sample overwrites

        hipLaunchKernelGGL(k_xt2, dim3(HWp / 64, 8), dim3(256), 0, stream,
                           z_real, z_imag, Xt_r, Xt_i);
        hipLaunchKernelGGL(k_conv1, dim3(2048), dim3(256), 0, stream, Xt_r, w1tb, b1, act);
        hipLaunchKernelGGL(k_conv2, dim3(8, 32, 4), dim3(256), 0, stream, act, w2, b2, dt, psi);
        hipLaunchKernelGGL(k_sample3, dim3(2048), dim3(256), 0, stream,
                           Xt_r, Xt_i, psi, out);
    } else {
        float* psi = (float*)(ws + 73728);
        f16* Xt  = (f16*)((char*)d_out + 4096);
        f16* act = (f16*)((char*)d_out + 4096 + PLANE);

        hipLaunchKernelGGL(k_xt2, dim3(HWp / 64, 4), dim3(256), 0, stream,
                           z_real, z_real, Xt, Xt);
        hipLaunchKernelGGL(k_conv1, dim3(2048), dim3(256), 0, stream, Xt, w1tb, b1, act);
        hipLaunchKernelGGL(k_conv2, dim3(8, 32, 4), dim3(256), 0, stream, act, w2, b2, dt, psi);
        hipLaunchKernelGGL(k_sample_fb, dim3(8, 32, 32), dim3(256), 0, stream,
                           z_real, z_imag, psi, out);
    }
}

// Round 10
// 169.569 us; speedup vs baseline: 1.0130x; 1.0130x over previous
//
#include <hip/hip_runtime.h>
#include <cmath>

namespace {
constexpr int H = 256, W = 256, HWp = H * W;
constexpr size_t PLANE = (size_t)4 * HWp * 64 * 2;  // one NHWC fp16 tensor, bytes
constexpr size_t NEED_FAST = 73728 + 2 * PLANE + (1u << 20);
}

typedef _Float16 f16;
typedef unsigned int u32;
typedef __attribute__((ext_vector_type(4))) _Float16 f16x4;
typedef __attribute__((ext_vector_type(8))) _Float16 f16x8;
typedef __attribute__((ext_vector_type(4))) float f32x4;
typedef __attribute__((ext_vector_type(4))) unsigned int u32x4;

__device__ __forceinline__ void dma16(const char* g, char* l) {
    __builtin_amdgcn_global_load_lds(
        (const __attribute__((address_space(1))) u32*)g,
        (__attribute__((address_space(3))) u32*)l, 16, 0, 0);
}

// K_xt2: NCHW fp32 -> NHWC fp16 for both tensors; last y-slice does the
// weight transform w1 [co][ci][3][3] fp32 -> w1tb [k9][co][ci] fp16.
__global__ __launch_bounds__(256) void k_xt2(const float* __restrict__ zr,
                                             const float* __restrict__ zi,
                                             f16* __restrict__ Xt_r,
                                             f16* __restrict__ Xt_i,
                                             const float* __restrict__ w1,
                                             f16* __restrict__ w1tb,
                                             int ny_xt) {
    if ((int)blockIdx.y == ny_xt) {           // weight-transform slice
        int i = blockIdx.x * 256 + threadIdx.x;
        if (i < 64 * 576) {
            int co = i / 576, r = i - co * 576;
            int ci = r / 9, k9 = r - ci * 9;
            w1tb[(k9 * 64 + co) * 64 + ci] = (f16)w1[i];
        }
        return;
    }
    __shared__ f16 tile[64][80];
    const int t = threadIdx.x;
    const int p0 = blockIdx.x * 64;
    const int bb = blockIdx.y & 3;
    const bool im = blockIdx.y >= 4;
    const float* x = im ? zi : zr;
    f16* dst = im ? Xt_i : Xt_r;
    const size_t base = (size_t)bb * 64 * HWp;
#pragma unroll
    for (int r = 0; r < 4; ++r) {
        int q = r * 256 + t;
        int ci = q >> 4, px4 = (q & 15) * 4;
        f32x4 v = *reinterpret_cast<const f32x4*>(x + base + (size_t)ci * HWp + p0 + px4);
#pragma unroll
        for (int j = 0; j < 4; ++j) tile[px4 + j][ci] = (f16)v[j];
    }
    __syncthreads();
    const int px = t >> 2, q = t & 3;
    u32x4* d = reinterpret_cast<u32x4*>(dst + ((size_t)bb * HWp + p0 + px) * 64 + q * 16);
    const u32x4* s = reinterpret_cast<const u32x4*>(&tile[px][q * 16]);
    d[0] = s[0];
    d[1] = s[1];
}

// K1 v5: conv1 via MFMA. W hoisted to registers ONCE per wave (36 x f16x8,
// fully static indexing); A-row only in LDS (18KB, global_load_lds + XOR
// swizzle). Block = 1 row x 128 px x 64 co; 4 waves (2px x 2co).
__global__ __launch_bounds__(256, 2) void k_conv1(
        const f16* __restrict__ Xt,    // [B][HWp][64] fp16
        const f16* __restrict__ w1tb,  // [9][64co][64ci] fp16
        const float* __restrict__ b1,
        f16* __restrict__ act) {       // [B][HWp][64] fp16
    __shared__ __align__(16) char lds[18432];

    const int tid = threadIdx.x;
    const int lane = tid & 63, wid = tid >> 6;
    const int lr = lane & 15, lg = lane >> 4;
    const int wpx = wid & 1, wco = wid >> 1;

    const int bid = blockIdx.x;                  // 0..2047
    const int swz = (bid & 7) * 256 + (bid >> 3);
    const int b = swz >> 9;
    const int y = (swz >> 1) & 255;
    const int x0 = (swz & 1) << 7;

    const int swzb = (lane ^ ((lane >> 3) & 7)) << 4;

    // ---- W prologue: all 36 fragments for this wave, coalesced 16B loads ----
    f16x8 Wreg[9][2][2];                         // [k9][n][c], static idx only
#pragma unroll
    for (int k9 = 0; k9 < 9; ++k9)
#pragma unroll
        for (int n = 0; n < 2; ++n)
#pragma unroll
            for (int c = 0; c < 2; ++c)
                Wreg[k9][n][c] = *reinterpret_cast<const f16x8*>(
                    w1tb + (size_t)(k9 * 64 + wco * 32 + n * 16 + lr) * 64
                         + c * 32 + lg * 8);

    f32x4 acc[4][2];
#pragma unroll
    for (int m = 0; m < 4; ++m)
#pragma unroll
        for (int n = 0; n < 2; ++n) acc[m][n] = (f32x4)0.f;

    const f16x8 zf = (f16x8)(f16)0.f;

#pragma unroll
    for (int dyi = 0; dyi < 3; ++dyi) {
        const int yy = y + dyi - 1;
        if ((unsigned)yy >= 256u) continue;      // block-uniform zero-pad skip

        __syncthreads();                          // LDS reuse guard
        {
            const char* asrc = (const char*)Xt +
                ((((size_t)b * 256 + yy) * 256 + x0 - 8) * 128) + swzb;
#pragma unroll
            for (int j = 0; j < 5; ++j) {
                const int jj = wid + j * 4;
                if (jj < 18) dma16(asrc + jj * 1024, lds + jj * 1024);
            }
        }
        __syncthreads();                          // drain DMA

#pragma unroll
        for (int kx = 0; kx < 3; ++kx) {
            const int dx = kx - 1;
            const int gx0 = x0 + wpx * 64 + lr + dx;
            const bool ok0 = (unsigned)gx0 < 256u;
            const bool ok3 = (unsigned)(gx0 + 48) < 256u;
            const int arow = (8 + wpx * 64 + lr + dx) << 7;
            const int axor = (lr + dx) & 7;
#pragma unroll
            for (int c = 0; c < 2; ++c) {
                const int abase = arow + (((c * 4 + lg) ^ axor) << 4);
                f16x8 A0 = *reinterpret_cast<const f16x8*>(lds + abase);
                f16x8 A1 = *reinterpret_cast<const f16x8*>(lds + abase + 2048);
                f16x8 A2 = *reinterpret_cast<const f16x8*>(lds + abase + 4096);
                f16x8 A3 = *reinterpret_cast<const f16x8*>(lds + abase + 6144);
                A0 = ok0 ? A0 : zf;
                A3 = ok3 ? A3 : zf;
                const f16x8 W0 = Wreg[dyi * 3 + kx][0][c];
                const f16x8 W1 = Wreg[dyi * 3 + kx][1][c];
                acc[0][0] = __builtin_amdgcn_mfma_f32_16x16x32_f16(W0, A0, acc[0][0], 0, 0, 0);
                acc[0][1] = __builtin_amdgcn_mfma_f32_16x16x32_f16(W1, A0, acc[0][1], 0, 0, 0);
                acc[1][0] = __builtin_amdgcn_mfma_f32_16x16x32_f16(W0, A1, acc[1][0], 0, 0, 0);
                acc[1][1] = __builtin_amdgcn_mfma_f32_16x16x32_f16(W1, A1, acc[1][1], 0, 0, 0);
                acc[2][0] = __builtin_amdgcn_mfma_f32_16x16x32_f16(W0, A2, acc[2][0], 0, 0, 0);
                acc[2][1] = __builtin_amdgcn_mfma_f32_16x16x32_f16(W1, A2, acc[2][1], 0, 0, 0);
                acc[3][0] = __builtin_amdgcn_mfma_f32_16x16x32_f16(W0, A3, acc[3][0], 0, 0, 0);
                acc[3][1] = __builtin_amdgcn_mfma_f32_16x16x32_f16(W1, A3, acc[3][1], 0, 0, 0);
            }
        }
    }

    float bias[2][4];
#pragma unroll
    for (int n = 0; n < 2; ++n) {
        f32x4 bv = *reinterpret_cast<const f32x4*>(b1 + wco * 32 + n * 16 + lg * 4);
#pragma unroll
        for (int r = 0; r < 4; ++r) bias[n][r] = bv[r];
    }
    const size_t row_base = ((size_t)b * 256 + y) * 256;
#pragma unroll
    for (int m = 0; m < 4; ++m) {
        f16* ap = act + (row_base + x0 + wpx * 64 + m * 16 + lr) * 64 + wco * 32 + lg * 4;
#pragma unroll
        for (int n = 0; n < 2; ++n) {
            f16x4 o;
#pragma unroll
            for (int r = 0; r < 4; ++r) {
                float v = acc[m][n][r] + bias[n][r];
                v = v / (1.f + __expf(-v));
                o[r] = (f16)v;
            }
            *reinterpret_cast<f16x4*>(ap + n * 16) = o;
        }
    }
}

// K2: conv2 (64->1) + *dt -> psi. NHWC fp16 input, f16x8 vector loads.
__global__ __launch_bounds__(256) void k_conv2(
        const f16* __restrict__ act, const float* __restrict__ w2,
        const float* __restrict__ b2, const float* __restrict__ dtp,
        float* __restrict__ psi) {
    const int tx = threadIdx.x & 31, ty = threadIdx.x >> 5;
    const int px = blockIdx.x * 32 + tx;
    const int py = blockIdx.y * 8 + ty;
    const int b = blockIdx.z;

    float a0 = 0.f, a1 = 0.f, a2 = 0.f, a3 = 0.f;
#pragma unroll
    for (int dy = -1; dy <= 1; ++dy) {
        const int yy = py + dy;
        if ((unsigned)yy >= (unsigned)H) continue;
#pragma unroll
        for (int dx = -1; dx <= 1; ++dx) {
            const int xx = px + dx;
            const int k9 = (dy + 1) * 3 + (dx + 1);
            if ((unsigned)xx < (unsigned)W) {
                const f16x8* ap = reinterpret_cast<const f16x8*>(
                    act + (((size_t)b * H + yy) * W + xx) * 64);
                const float* wp = w2 + k9;
#pragma unroll
                for (int g = 0; g < 8; ++g) {
                    const f16x8 v = ap[g];
                    const int cb = g * 8;
                    a0 = fmaf((float)v[0], wp[(cb + 0) * 9], a0);
                    a1 = fmaf((float)v[1], wp[(cb + 1) * 9], a1);
                    a2 = fmaf((float)v[2], wp[(cb + 2) * 9], a2);
                    a3 = fmaf((float)v[3], wp[(cb + 3) * 9], a3);
                    a0 = fmaf((float)v[4], wp[(cb + 4) * 9], a0);
                    a1 = fmaf((float)v[5], wp[(cb + 5) * 9], a1);
                    a2 = fmaf((float)v[6], wp[(cb + 6) * 9], a2);
                    a3 = fmaf((float)v[7], wp[(cb + 7) * 9], a3);
                }
            }
        }
    }
    psi[((size_t)b * H + py) * W + px] = ((a0 + a1) + (a2 + a3) + b2[0]) * dtp[0];
}

// K3 v3: block = 1 row-half (128 px) x ALL 128 channels (proven R8).
__global__ __launch_bounds__(256, 4) void k_sample3(
        const f16* __restrict__ Xt_r, const f16* __restrict__ Xt_i,
        const float* __restrict__ psi, float* __restrict__ out) {
    __shared__ int   s_off[4][128];
    __shared__ float s_w[4][128];
    __shared__ __align__(16) float s_stage[64][132];

    const int tid = threadIdx.x;
    const int bid = blockIdx.x;                  // 0..2047
    const int swz = (bid & 7) * 256 + (bid >> 3);
    const int seg = swz & 1, y = (swz >> 1) & 255, b = swz >> 9;
    const int x0 = seg * 128;

    if (tid < 128) {
        const int px = x0 + tid;
        const float* pb = psi + b * HWp;
        const int yp = min(y + 1, H - 1), ym = max(y - 1, 0);
        const int xp = min(px + 1, W - 1), xm = max(px - 1, 0);
        const float u = 0.5f * (pb[yp * W + px] - pb[ym * W + px]);
        const float v = -0.5f * (pb[y * W + xp] - pb[y * W + xm]);
        const float gx = (-1.f + 2.f * px / (float)(W - 1)) - u * (2.f / (float)W);
        const float gy = (-1.f + 2.f * y / (float)(H - 1)) - v * (2.f / (float)H);
        float ix = fminf(fmaxf((gx + 1.f) * 0.5f * (float)(W - 1), 0.f), (float)(W - 1));
        float iy = fminf(fmaxf((gy + 1.f) * 0.5f * (float)(H - 1), 0.f), (float)(H - 1));
        const float xf = floorf(ix), yf = floorf(iy);
        const float wx = ix - xf, wy = iy - yf;
        const int ix0 = (int)xf, iy0 = (int)yf;
        const int ix1 = min(ix0 + 1, W - 1), iy1 = min(iy0 + 1, H - 1);
        s_off[0][tid] = (iy0 * W + ix0) * 128;
        s_off[1][tid] = (iy0 * W + ix1) * 128;
        s_off[2][tid] = (iy1 * W + ix0) * 128;
        s_off[3][tid] = (iy1 * W + ix1) * 128;
        s_w[0][tid] = (1.f - wx) * (1.f - wy);
        s_w[1][tid] = wx * (1.f - wy);
        s_w[2][tid] = (1.f - wx) * wy;
        s_w[3][tid] = wx * wy;
    }
    __syncthreads();

    const int p = tid >> 1, s = tid & 1;
    const int o0 = s_off[0][p], o1 = s_off[1][p], o2 = s_off[2][p], o3 = s_off[3][p];
    const float w0 = s_w[0][p], w1 = s_w[1][p], w2 = s_w[2][p], w3 = s_w[3][p];
    const int cl = tid >> 5;
    const int pxq = (tid & 31) * 4;
    const size_t obase = (size_t)b * 128 * HWp + (size_t)y * W + x0 + pxq;

#pragma unroll
    for (int pl = 0; pl < 2; ++pl) {
        const char* base = (const char*)(pl ? Xt_i : Xt_r)
                         + (size_t)b * HWp * 128 + s * 64;
        const char* c0 = base + o0;
        const char* c1 = base + o1;
        const char* c2 = base + o2;
        const char* c3 = base + o3;
        f16x8 h00 = *(const f16x8*)(c0);      f16x8 h01 = *(const f16x8*)(c0 + 16);
        f16x8 h02 = *(const f16x8*)(c0 + 32); f16x8 h03 = *(const f16x8*)(c0 + 48);
        f16x8 h10 = *(const f16x8*)(c1);      f16x8 h11 = *(const f16x8*)(c1 + 16);
        f16x8 h12 = *(const f16x8*)(c1 + 32); f16x8 h13 = *(const f16x8*)(c1 + 48);
        f16x8 h20 = *(const f16x8*)(c2);      f16x8 h21 = *(const f16x8*)(c2 + 16);
        f16x8 h22 = *(const f16x8*)(c2 + 32); f16x8 h23 = *(const f16x8*)(c2 + 48);
        f16x8 h30 = *(const f16x8*)(c3);      f16x8 h31 = *(const f16x8*)(c3 + 16);
        f16x8 h32 = *(const f16x8*)(c3 + 32); f16x8 h33 = *(const f16x8*)(c3 + 48);

        const int rb = s << 5;
#pragma unroll
        for (int k = 0; k < 8; ++k) {
            s_stage[rb + k][p] = w0 * (float)h00[k] + w1 * (float)h10[k]
                               + w2 * (float)h20[k] + w3 * (float)h30[k];
            s_stage[rb + 8 + k][p] = w0 * (float)h01[k] + w1 * (float)h11[k]
                                   + w2 * (float)h21[k] + w3 * (float)h31[k];
            s_stage[rb + 16 + k][p] = w0 * (float)h02[k] + w1 * (float)h12[k]
                                    + w2 * (float)h22[k] + w3 * (float)h32[k];
            s_stage[rb + 24 + k][p] = w0 * (float)h03[k] + w1 * (float)h13[k]
                                    + w2 * (float)h23[k] + w3 * (float)h33[k];
        }
        __syncthreads();
#pragma unroll
        for (int k = 0; k < 8; ++k) {
            const int c = cl + (k << 3);
            f32x4 vv = *(const f32x4*)&s_stage[c][pxq];
            *(f32x4*)(out + obase + (size_t)(pl * 64 + c) * HWp) = vv;
        }
        __syncthreads();
    }
}

// K3 fallback: scalar gather from fp32 NCHW.
__global__ __launch_bounds__(256) void k_sample_fb(
        const float* __restrict__ zr, const float* __restrict__ zi,
        const float* __restrict__ psi, float* __restrict__ out) {
    const int tx = threadIdx.x & 31, ty = threadIdx.x >> 5;
    const int px = blockIdx.x * 32 + tx;
    const int py = blockIdx.y * 8 + ty;
    const int b  = blockIdx.z >> 3;
    const int c0 = (blockIdx.z & 7) * 16;

    const float* pb = psi + b * HWp;
    const int yp = min(py + 1, H - 1), ym = max(py - 1, 0);
    const int xp = min(px + 1, W - 1), xm = max(px - 1, 0);
    const float u = 0.5f * (pb[yp * W + px] - pb[ym * W + px]);
    const float v = -0.5f * (pb[py * W + xp] - pb[py * W + xm]);

    const float gx = (-1.f + 2.f * px / (float)(W - 1)) - u * (2.f / (float)W);
    const float gy = (-1.f + 2.f * py / (float)(H - 1)) - v * (2.f / (float)H);

    float ix = fminf(fmaxf((gx + 1.f) * 0.5f * (float)(W - 1), 0.f), (float)(W - 1));
    float iy = fminf(fmaxf((gy + 1.f) * 0.5f * (float)(H - 1), 0.f), (float)(H - 1));
    const float xf = floorf(ix), yf = floorf(iy);
    const float wx = ix - xf, wy = iy - yf;
    const int ix0 = (int)xf, iy0 = (int)yf;
    const int ix1 = min(ix0 + 1, W - 1), iy1 = min(iy0 + 1, H - 1);

    const int o00 = iy0 * W + ix0, o01 = iy0 * W + ix1;
    const int o10 = iy1 * W + ix0, o11 = iy1 * W + ix1;
    const float w00 = (1.f - wx) * (1.f - wy), w01 = wx * (1.f - wy);
    const float w10 = (1.f - wx) * wy, w11 = wx * wy;

    const float* src0 = (c0 < 64) ? (zr + (size_t)b * 64 * HWp + (size_t)c0 * HWp)
                                  : (zi + (size_t)b * 64 * HWp + (size_t)(c0 - 64) * HWp);
    float* ob = out + ((size_t)b * 128 + c0) * HWp + py * W + px;
#pragma unroll
    for (int c = 0; c < 16; ++c) {
        const float* p = src0 + (size_t)c * HWp;
        ob[(size_t)c * HWp] = p[o00] * w00 + p[o01] * w01 + p[o10] * w10 + p[o11] * w11;
    }
}

extern "C" void kernel_launch(void* const* d_in, const int* in_sizes, int n_in,
                              void* d_out, int out_size, void* d_ws, size_t ws_size,
                              hipStream_t stream) {
    const float* z_real = (const float*)d_in[0];
    const float* z_imag = (const float*)d_in[1];
    const float* dt     = (const float*)d_in[2];
    const float* w1     = (const float*)d_in[3];
    const float* b1     = (const float*)d_in[4];
    const float* w2     = (const float*)d_in[5];
    const float* b2     = (const float*)d_in[6];

    float* out = (float*)d_out;
    char* ws = (char*)d_ws;
    f16* w1tb = (f16*)ws;                       // 73728 B

    if (ws_size >= NEED_FAST) {
        // ws layout: w1tb | Xt_r | Xt_i | psi
        f16* Xt_r  = (f16*)(ws + 73728);
        f16* Xt_i  = (f16*)(ws + 73728 + PLANE);
        float* psi = (float*)(ws + 73728 + 2 * PLANE);
        f16* act   = (f16*)d_out;   // consumed by conv2 before sample overwrites

        hipLaunchKernelGGL(k_xt2, dim3(HWp / 64, 9), dim3(256), 0, stream,
                           z_real, z_imag, Xt_r, Xt_i, w1, w1tb, 8);
        hipLaunchKernelGGL(k_conv1, dim3(2048), dim3(256), 0, stream, Xt_r, w1tb, b1, act);
        hipLaunchKernelGGL(k_conv2, dim3(8, 32, 4), dim3(256), 0, stream, act, w2, b2, dt, psi);
        hipLaunchKernelGGL(k_sample3, dim3(2048), dim3(256), 0, stream,
                           Xt_r, Xt_i, psi, out);
    } else {
        float* psi = (float*)(ws + 73728);
        f16* Xt  = (f16*)((char*)d_out + 4096);
        f16* act = (f16*)((char*)d_out + 4096 + PLANE);

        hipLaunchKernelGGL(k_xt2, dim3(HWp / 64, 5), dim3(256), 0, stream,
                           z_real, z_real, Xt, Xt, w1, w1tb, 4);
        hipLaunchKernelGGL(k_conv1, dim3(2048), dim3(256), 0, stream, Xt, w1tb, b1, act);
        hipLaunchKernelGGL(k_conv2, dim3(8, 32, 4), dim3(256), 0, stream, act, w2, b2, dt, psi);
        hipLaunchKernelGGL(k_sample_fb, dim3(8, 32, 32), dim3(256), 0, stream,
                           z_real, z_imag, psi, out);
    }
}

// Round 11
// 159.896 us; speedup vs baseline: 1.0742x; 1.0605x over previous
//
#include <hip/hip_runtime.h>
#include <cmath>

namespace {
constexpr int H = 256, W = 256, HWp = H * W;
constexpr size_t PLANE = (size_t)4 * HWp * 64 * 2;  // one NHWC fp16 tensor, bytes
constexpr size_t NEED_FAST = 73728 + 2 * PLANE + (1u << 20);
}

typedef _Float16 f16;
typedef unsigned int u32;
typedef __attribute__((ext_vector_type(4))) _Float16 f16x4;
typedef __attribute__((ext_vector_type(8))) _Float16 f16x8;
typedef __attribute__((ext_vector_type(4))) float f32x4;
typedef __attribute__((ext_vector_type(4))) unsigned int u32x4;

__device__ __forceinline__ void dma16(const char* g, char* l) {
    __builtin_amdgcn_global_load_lds(
        (const __attribute__((address_space(1))) u32*)g,
        (__attribute__((address_space(3))) u32*)l, 16, 0, 0);
}

// K_xt2: NCHW fp32 -> NHWC fp16 for both tensors; last y-slice does the
// weight transform w1 [co][ci][3][3] fp32 -> w1tb [k9][co][ci] fp16.
__global__ __launch_bounds__(256) void k_xt2(const float* __restrict__ zr,
                                             const float* __restrict__ zi,
                                             f16* __restrict__ Xt_r,
                                             f16* __restrict__ Xt_i,
                                             const float* __restrict__ w1,
                                             f16* __restrict__ w1tb,
                                             int ny_xt) {
    if ((int)blockIdx.y == ny_xt) {           // weight-transform slice
        int i = blockIdx.x * 256 + threadIdx.x;
        if (i < 64 * 576) {
            int co = i / 576, r = i - co * 576;
            int ci = r / 9, k9 = r - ci * 9;
            w1tb[(k9 * 64 + co) * 64 + ci] = (f16)w1[i];
        }
        return;
    }
    __shared__ f16 tile[64][80];
    const int t = threadIdx.x;
    const int p0 = blockIdx.x * 64;
    const int bb = blockIdx.y & 3;
    const bool im = blockIdx.y >= 4;
    const float* x = im ? zi : zr;
    f16* dst = im ? Xt_i : Xt_r;
    const size_t base = (size_t)bb * 64 * HWp;
#pragma unroll
    for (int r = 0; r < 4; ++r) {
        int q = r * 256 + t;
        int ci = q >> 4, px4 = (q & 15) * 4;
        f32x4 v = *reinterpret_cast<const f32x4*>(x + base + (size_t)ci * HWp + p0 + px4);
#pragma unroll
        for (int j = 0; j < 4; ++j) tile[px4 + j][ci] = (f16)v[j];
    }
    __syncthreads();
    const int px = t >> 2, q = t & 3;
    u32x4* d = reinterpret_cast<u32x4*>(dst + ((size_t)bb * HWp + p0 + px) * 64 + q * 16);
    const u32x4* s = reinterpret_cast<const u32x4*>(&tile[px][q * 16]);
    d[0] = s[0];
    d[1] = s[1];
}

// K1 v6: conv1, row-marching ring. Block = full 256-px row x 64 co x 4 rows.
// 512 threads = 8 waves (4 px-groups x 2 co-groups). LDS = 4-slot ring of
// full input rows (4 x 32 KB), each row staged ONCE via global_load_lds with
// XOR-swizzled source; W in registers (36 frags). One barrier per output row.
__global__ __launch_bounds__(512, 1) void k_conv1(
        const f16* __restrict__ Xt,    // [B][HWp][64] fp16
        const f16* __restrict__ w1tb,  // [9][64co][64ci] fp16
        const float* __restrict__ b1,
        f16* __restrict__ act) {       // [B][HWp][64] fp16
    __shared__ __align__(16) char lds[131072];   // 4 ring slots x 32 KB

    const int tid = threadIdx.x;
    const int lane = tid & 63, wid = tid >> 6;
    const int lr = lane & 15, lg = lane >> 4;
    const int pg = wid & 3, cg = wid >> 2;       // 64-px group, 32-co group

    const int bid = blockIdx.x;                  // 0..255
    const int swz = (bid & 7) * 32 + (bid >> 3); // XCD-contiguous row-quads
    const int b = swz >> 6;
    const int y0 = (swz & 63) * 4;

    const int swzb = (lane ^ ((lane >> 3) & 7)) << 4;
    const size_t img = (size_t)b * 256;

    // ---- W prologue: co = cg*32 + n*16 + lr, ci chunk c*32 + lg*8 ----
    f16x8 Wreg[9][2][2];
#pragma unroll
    for (int k9 = 0; k9 < 9; ++k9)
#pragma unroll
        for (int n = 0; n < 2; ++n)
#pragma unroll
            for (int c = 0; c < 2; ++c)
                Wreg[k9][n][c] = *reinterpret_cast<const f16x8*>(
                    w1tb + (size_t)(k9 * 64 + cg * 32 + n * 16 + lr) * 64
                         + c * 32 + lg * 8);

    float bias[2][4];
#pragma unroll
    for (int n = 0; n < 2; ++n) {
        f32x4 bv = *reinterpret_cast<const f32x4*>(b1 + cg * 32 + n * 16 + lg * 4);
#pragma unroll
        for (int r = 0; r < 4; ++r) bias[n][r] = bv[r];
    }

    // stage one full input row (32 KB) into ring slot yy&3; block-uniform.
    auto stage = [&](int yy) {
        const char* src = (const char*)Xt + ((img + yy) * 256) * 128 + swzb;
        char* dst = lds + (yy & 3) * 32768;
#pragma unroll
        for (int i = 0; i < 4; ++i) {
            const int ch = wid + i * 8;          // 32 chunks of 1 KB
            dma16(src + ch * 1024, dst + ch * 1024);
        }
    };

    if (y0 > 0) stage(y0 - 1);
    stage(y0);
    stage(y0 + 1);
    __syncthreads();

    const f16x8 zf = (f16x8)(f16)0.f;

    for (int r = 0; r < 4; ++r) {
        const int y = y0 + r;
        const int yn = y + 2;
        if (r < 3 && yn < 256) stage(yn);        // slot (y+2)&3: disjoint from reads

        f32x4 acc[4][2];
#pragma unroll
        for (int m = 0; m < 4; ++m)
#pragma unroll
            for (int n = 0; n < 2; ++n) acc[m][n] = (f32x4)0.f;

#pragma unroll
        for (int dyi = 0; dyi < 3; ++dyi) {
            const int yy = y + dyi - 1;
            if ((unsigned)yy >= 256u) continue;  // image-edge zero pad (uniform)
            const char* sb = lds + (yy & 3) * 32768;
#pragma unroll
            for (int kx = 0; kx < 3; ++kx) {
                const int dx = kx - 1;
                const int px1 = pg * 64 + 16 + lr + dx;          // m=1 (always in)
                const bool ok0 = (unsigned)(px1 - 16) < 256u;    // m=0 edge
                const bool ok3 = (unsigned)(px1 + 32) < 256u;    // m=3 edge
                const int px0 = ok0 ? px1 - 16 : px1 - 16 - dx;  // clamped addr
                const int px2 = px1 + 16;
                const int px3 = ok3 ? px1 + 32 : px1 + 32 - dx;
                const int k9 = dyi * 3 + kx;
#pragma unroll
                for (int c = 0; c < 2; ++c) {
                    const int pe = c * 4 + lg;
                    f16x8 A0 = *(const f16x8*)(sb + (px0 << 7) + ((pe ^ (px0 & 7)) << 4));
                    f16x8 A1 = *(const f16x8*)(sb + (px1 << 7) + ((pe ^ (px1 & 7)) << 4));
                    f16x8 A2 = *(const f16x8*)(sb + (px2 << 7) + ((pe ^ (px2 & 7)) << 4));
                    f16x8 A3 = *(const f16x8*)(sb + (px3 << 7) + ((pe ^ (px3 & 7)) << 4));
                    A0 = ok0 ? A0 : zf;
                    A3 = ok3 ? A3 : zf;
                    const f16x8 W0 = Wreg[k9][0][c];
                    const f16x8 W1 = Wreg[k9][1][c];
                    acc[0][0] = __builtin_amdgcn_mfma_f32_16x16x32_f16(W0, A0, acc[0][0], 0, 0, 0);
                    acc[0][1] = __builtin_amdgcn_mfma_f32_16x16x32_f16(W1, A0, acc[0][1], 0, 0, 0);
                    acc[1][0] = __builtin_amdgcn_mfma_f32_16x16x32_f16(W0, A1, acc[1][0], 0, 0, 0);
                    acc[1][1] = __builtin_amdgcn_mfma_f32_16x16x32_f16(W1, A1, acc[1][1], 0, 0, 0);
                    acc[2][0] = __builtin_amdgcn_mfma_f32_16x16x32_f16(W0, A2, acc[2][0], 0, 0, 0);
                    acc[2][1] = __builtin_amdgcn_mfma_f32_16x16x32_f16(W1, A2, acc[2][1], 0, 0, 0);
                    acc[3][0] = __builtin_amdgcn_mfma_f32_16x16x32_f16(W0, A3, acc[3][0], 0, 0, 0);
                    acc[3][1] = __builtin_amdgcn_mfma_f32_16x16x32_f16(W1, A3, acc[3][1], 0, 0, 0);
                }
            }
        }

        // epilogue row y: px = pg*64 + m*16 + lr, co = cg*32 + n*16 + lg*4 + r
        const size_t rb = (img + y) * 256;
#pragma unroll
        for (int m = 0; m < 4; ++m) {
            f16* ap = act + (rb + pg * 64 + m * 16 + lr) * 64 + cg * 32 + lg * 4;
#pragma unroll
            for (int n = 0; n < 2; ++n) {
                f16x4 o;
#pragma unroll
                for (int q = 0; q < 4; ++q) {
                    float v = acc[m][n][q] + bias[n][q];
                    v = v / (1.f + __expf(-v));
                    o[q] = (f16)v;
                }
                *reinterpret_cast<f16x4*>(ap + n * 16) = o;
            }
        }
        __syncthreads();   // drains this iter's DMA; frees slots for next iter
    }
}

// K2: conv2 (64->1) + *dt -> psi. NHWC fp16 input, f16x8 vector loads.
__global__ __launch_bounds__(256) void k_conv2(
        const f16* __restrict__ act, const float* __restrict__ w2,
        const float* __restrict__ b2, const float* __restrict__ dtp,
        float* __restrict__ psi) {
    const int tx = threadIdx.x & 31, ty = threadIdx.x >> 5;
    const int px = blockIdx.x * 32 + tx;
    const int py = blockIdx.y * 8 + ty;
    const int b = blockIdx.z;

    float a0 = 0.f, a1 = 0.f, a2 = 0.f, a3 = 0.f;
#pragma unroll
    for (int dy = -1; dy <= 1; ++dy) {
        const int yy = py + dy;
        if ((unsigned)yy >= (unsigned)H) continue;
#pragma unroll
        for (int dx = -1; dx <= 1; ++dx) {
            const int xx = px + dx;
            const int k9 = (dy + 1) * 3 + (dx + 1);
            if ((unsigned)xx < (unsigned)W) {
                const f16x8* ap = reinterpret_cast<const f16x8*>(
                    act + (((size_t)b * H + yy) * W + xx) * 64);
                const float* wp = w2 + k9;
#pragma unroll
                for (int g = 0; g < 8; ++g) {
                    const f16x8 v = ap[g];
                    const int cb = g * 8;
                    a0 = fmaf((float)v[0], wp[(cb + 0) * 9], a0);
                    a1 = fmaf((float)v[1], wp[(cb + 1) * 9], a1);
                    a2 = fmaf((float)v[2], wp[(cb + 2) * 9], a2);
                    a3 = fmaf((float)v[3], wp[(cb + 3) * 9], a3);
                    a0 = fmaf((float)v[4], wp[(cb + 4) * 9], a0);
                    a1 = fmaf((float)v[5], wp[(cb + 5) * 9], a1);
                    a2 = fmaf((float)v[6], wp[(cb + 6) * 9], a2);
                    a3 = fmaf((float)v[7], wp[(cb + 7) * 9], a3);
                }
            }
        }
    }
    psi[((size_t)b * H + py) * W + px] = ((a0 + a1) + (a2 + a3) + b2[0]) * dtp[0];
}

// K3 v3: block = 1 row-half (128 px) x ALL 128 channels (proven R8).
__global__ __launch_bounds__(256, 4) void k_sample3(
        const f16* __restrict__ Xt_r, const f16* __restrict__ Xt_i,
        const float* __restrict__ psi, float* __restrict__ out) {
    __shared__ int   s_off[4][128];
    __shared__ float s_w[4][128];
    __shared__ __align__(16) float s_stage[64][132];

    const int tid = threadIdx.x;
    const int bid = blockIdx.x;                  // 0..2047
    const int swz = (bid & 7) * 256 + (bid >> 3);
    const int seg = swz & 1, y = (swz >> 1) & 255, b = swz >> 9;
    const int x0 = seg * 128;

    if (tid < 128) {
        const int px = x0 + tid;
        const float* pb = psi + b * HWp;
        const int yp = min(y + 1, H - 1), ym = max(y - 1, 0);
        const int xp = min(px + 1, W - 1), xm = max(px - 1, 0);
        const float u = 0.5f * (pb[yp * W + px] - pb[ym * W + px]);
        const float v = -0.5f * (pb[y * W + xp] - pb[y * W + xm]);
        const float gx = (-1.f + 2.f * px / (float)(W - 1)) - u * (2.f / (float)W);
        const float gy = (-1.f + 2.f * y / (float)(H - 1)) - v * (2.f / (float)H);
        float ix = fminf(fmaxf((gx + 1.f) * 0.5f * (float)(W - 1), 0.f), (float)(W - 1));
        float iy = fminf(fmaxf((gy + 1.f) * 0.5f * (float)(H - 1), 0.f), (float)(H - 1));
        const float xf = floorf(ix), yf = floorf(iy);
        const float wx = ix - xf, wy = iy - yf;
        const int ix0 = (int)xf, iy0 = (int)yf;
        const int ix1 = min(ix0 + 1, W - 1), iy1 = min(iy0 + 1, H - 1);
        s_off[0][tid] = (iy0 * W + ix0) * 128;
        s_off[1][tid] = (iy0 * W + ix1) * 128;
        s_off[2][tid] = (iy1 * W + ix0) * 128;
        s_off[3][tid] = (iy1 * W + ix1) * 128;
        s_w[0][tid] = (1.f - wx) * (1.f - wy);
        s_w[1][tid] = wx * (1.f - wy);
        s_w[2][tid] = (1.f - wx) * wy;
        s_w[3][tid] = wx * wy;
    }
    __syncthreads();

    const int p = tid >> 1, s = tid & 1;
    const int o0 = s_off[0][p], o1 = s_off[1][p], o2 = s_off[2][p], o3 = s_off[3][p];
    const float w0 = s_w[0][p], w1 = s_w[1][p], w2 = s_w[2][p], w3 = s_w[3][p];
    const int cl = tid >> 5;
    const int pxq = (tid & 31) * 4;
    const size_t obase = (size_t)b * 128 * HWp + (size_t)y * W + x0 + pxq;

#pragma unroll
    for (int pl = 0; pl < 2; ++pl) {
        const char* base = (const char*)(pl ? Xt_i : Xt_r)
                         + (size_t)b * HWp * 128 + s * 64;
        const char* c0 = base + o0;
        const char* c1 = base + o1;
        const char* c2 = base + o2;
        const char* c3 = base + o3;
        f16x8 h00 = *(const f16x8*)(c0);      f16x8 h01 = *(const f16x8*)(c0 + 16);
        f16x8 h02 = *(const f16x8*)(c0 + 32); f16x8 h03 = *(const f16x8*)(c0 + 48);
        f16x8 h10 = *(const f16x8*)(c1);      f16x8 h11 = *(const f16x8*)(c1 + 16);
        f16x8 h12 = *(const f16x8*)(c1 + 32); f16x8 h13 = *(const f16x8*)(c1 + 48);
        f16x8 h20 = *(const f16x8*)(c2);      f16x8 h21 = *(const f16x8*)(c2 + 16);
        f16x8 h22 = *(const f16x8*)(c2 + 32); f16x8 h23 = *(const f16x8*)(c2 + 48);
        f16x8 h30 = *(const f16x8*)(c3);      f16x8 h31 = *(const f16x8*)(c3 + 16);
        f16x8 h32 = *(const f16x8*)(c3 + 32); f16x8 h33 = *(const f16x8*)(c3 + 48);

        const int rb = s << 5;
#pragma unroll
        for (int k = 0; k < 8; ++k) {
            s_stage[rb + k][p] = w0 * (float)h00[k] + w1 * (float)h10[k]
                               + w2 * (float)h20[k] + w3 * (float)h30[k];
            s_stage[rb + 8 + k][p] = w0 * (float)h01[k] + w1 * (float)h11[k]
                                   + w2 * (float)h21[k] + w3 * (float)h31[k];
            s_stage[rb + 16 + k][p] = w0 * (float)h02[k] + w1 * (float)h12[k]
                                    + w2 * (float)h22[k] + w3 * (float)h32[k];
            s_stage[rb + 24 + k][p] = w0 * (float)h03[k] + w1 * (float)h13[k]
                                    + w2 * (float)h23[k] + w3 * (float)h33[k];
        }
        __syncthreads();
#pragma unroll
        for (int k = 0; k < 8; ++k) {
            const int c = cl + (k << 3);
            f32x4 vv = *(const f32x4*)&s_stage[c][pxq];
            *(f32x4*)(out + obase + (size_t)(pl * 64 + c) * HWp) = vv;
        }
        __syncthreads();
    }
}

// K3 fallback: scalar gather from fp32 NCHW.
__global__ __launch_bounds__(256) void k_sample_fb(
        const float* __restrict__ zr, const float* __restrict__ zi,
        const float* __restrict__ psi, float* __restrict__ out) {
    const int tx = threadIdx.x & 31, ty = threadIdx.x >> 5;
    const int px = blockIdx.x * 32 + tx;
    const int py = blockIdx.y * 8 + ty;
    const int b  = blockIdx.z >> 3;
    const int c0 = (blockIdx.z & 7) * 16;

    const float* pb = psi + b * HWp;
    const int yp = min(py + 1, H - 1), ym = max(py - 1, 0);
    const int xp = min(px + 1, W - 1), xm = max(px - 1, 0);
    const float u = 0.5f * (pb[yp * W + px] - pb[ym * W + px]);
    const float v = -0.5f * (pb[py * W + xp] - pb[py * W + xm]);

    const float gx = (-1.f + 2.f * px / (float)(W - 1)) - u * (2.f / (float)W);
    const float gy = (-1.f + 2.f * py / (float)(H - 1)) - v * (2.f / (float)H);

    float ix = fminf(fmaxf((gx + 1.f) * 0.5f * (float)(W - 1), 0.f), (float)(W - 1));
    float iy = fminf(fmaxf((gy + 1.f) * 0.5f * (float)(H - 1), 0.f), (float)(H - 1));
    const float xf = floorf(ix), yf = floorf(iy);
    const float wx = ix - xf, wy = iy - yf;
    const int ix0 = (int)xf, iy0 = (int)yf;
    const int ix1 = min(ix0 + 1, W - 1), iy1 = min(iy0 + 1, H - 1);

    const int o00 = iy0 * W + ix0, o01 = iy0 * W + ix1;
    const int o10 = iy1 * W + ix0, o11 = iy1 * W + ix1;
    const float w00 = (1.f - wx) * (1.f - wy), w01 = wx * (1.f - wy);
    const float w10 = (1.f - wx) * wy, w11 = wx * wy;

    const float* src0 = (c0 < 64) ? (zr + (size_t)b * 64 * HWp + (size_t)c0 * HWp)
                                  : (zi + (size_t)b * 64 * HWp + (size_t)(c0 - 64) * HWp);
    float* ob = out + ((size_t)b * 128 + c0) * HWp + py * W + px;
#pragma unroll
    for (int c = 0; c < 16; ++c) {
        const float* p = src0 + (size_t)c * HWp;
        ob[(size_t)c * HWp] = p[o00] * w00 + p[o01] * w01 + p[o10] * w10 + p[o11] * w11;
    }
}

extern "C" void kernel_launch(void* const* d_in, const int* in_sizes, int n_in,
                              void* d_out, int out_size, void* d_ws, size_t ws_size,
                              hipStream_t stream) {
    const float* z_real = (const float*)d_in[0];
    const float* z_imag = (const float*)d_in[1];
    const float* dt     = (const float*)d_in[2];
    const float* w1     = (const float*)d_in[3];
    const float* b1     = (const float*)d_in[4];
    const float* w2     = (const float*)d_in[5];
    const float* b2     = (const float*)d_in[6];

    float* out = (float*)d_out;
    char* ws = (char*)d_ws;
    f16* w1tb = (f16*)ws;                       // 73728 B

    if (ws_size >= NEED_FAST) {
        // ws layout: w1tb | Xt_r | Xt_i | psi
        f16* Xt_r  = (f16*)(ws + 73728);
        f16* Xt_i  = (f16*)(ws + 73728 + PLANE);
        float* psi = (float*)(ws + 73728 + 2 * PLANE);
        f16* act   = (f16*)d_out;   // consumed by conv2 before sample overwrites

        hipLaunchKernelGGL(k_xt2, dim3(HWp / 64, 9), dim3(256), 0, stream,
                           z_real, z_imag, Xt_r, Xt_i, w1, w1tb, 8);
        hipLaunchKernelGGL(k_conv1, dim3(256), dim3(512), 0, stream, Xt_r, w1tb, b1, act);
        hipLaunchKernelGGL(k_conv2, dim3(8, 32, 4), dim3(256), 0, stream, act, w2, b2, dt, psi);
        hipLaunchKernelGGL(k_sample3, dim3(2048), dim3(256), 0, stream,
                           Xt_r, Xt_i, psi, out);
    } else {
        float* psi = (float*)(ws + 73728);
        f16* Xt  = (f16*)((char*)d_out + 4096);
        f16* act = (f16*)((char*)d_out + 4096 + PLANE);

        hipLaunchKernelGGL(k_xt2, dim3(HWp / 64, 5), dim3(256), 0, stream,
                           z_real, z_real, Xt, Xt, w1, w1tb, 4);
        hipLaunchKernelGGL(k_conv1, dim3(256), dim3(512), 0, stream, Xt, w1tb, b1, act);
        hipLaunchKernelGGL(k_conv2, dim3(8, 32, 4), dim3(256), 0, stream, act, w2, b2, dt, psi);
        hipLaunchKernelGGL(k_sample_fb, dim3(8, 32, 32), dim3(256), 0, stream,
                           z_real, z_imag, psi, out);
    }
}